// Round 1
// baseline (47.583 us; speedup 1.0000x reference)
//
#include <hip/hip_runtime.h>

// CSR per-head weighted gather + segment-sum.
//   out[n,h,d] = sum_{e in [row_ptr[n], row_ptr[n+1])} node_feat[col_idx[e],h,d] * edge_weight[e,h]
// Shapes: row_ptr (N+1,), col_idx (E,), edge_weight (E,8) f32, node_feat (N,8,32) f32.
// Strategy: one 64-lane wave per destination node. Lane l handles head h=l>>3,
// dims [d4, d4+4) with d4=(l&7)*4 -> the wave covers the full 256-float output
// row; each node_feat gather is a contiguous 1 KiB row read (16B/lane, coalesced).

#define GAT_H 8
#define GAT_D 32
#define GAT_ROW (GAT_H * GAT_D)   // 256 floats per node

__device__ __forceinline__ void fma4(float4& acc, const float4& f, float w) {
    acc.x = fmaf(f.x, w, acc.x);
    acc.y = fmaf(f.y, w, acc.y);
    acc.z = fmaf(f.z, w, acc.z);
    acc.w = fmaf(f.w, w, acc.w);
}

__global__ __launch_bounds__(256) void gat_gather_kernel(
    const int*   __restrict__ row_ptr,
    const int*   __restrict__ col_idx,
    const float* __restrict__ edge_weight,
    const float* __restrict__ node_feat,
    float*       __restrict__ out,
    int num_nodes)
{
    const int wave = threadIdx.x >> 6;                  // 0..3
    const int lane = threadIdx.x & 63;
    const int node = blockIdx.x * 4 + wave;
    if (node >= num_nodes) return;

    const int h   = lane >> 3;                          // 0..7
    const int d4  = (lane & 7) << 2;                    // 0,4,...,28
    const int off = h * GAT_D + d4;                     // lane's offset within a row

    const int beg = row_ptr[node];
    const int end = row_ptr[node + 1];

    float4 acc = make_float4(0.f, 0.f, 0.f, 0.f);

    int e = beg;
    // Unroll x4: issue 4 independent gathers + weights per iteration for ILP.
    for (; e + 4 <= end; e += 4) {
        const int s0 = col_idx[e + 0];
        const int s1 = col_idx[e + 1];
        const int s2 = col_idx[e + 2];
        const int s3 = col_idx[e + 3];
        const float w0 = edge_weight[(size_t)(e + 0) * GAT_H + h];
        const float w1 = edge_weight[(size_t)(e + 1) * GAT_H + h];
        const float w2 = edge_weight[(size_t)(e + 2) * GAT_H + h];
        const float w3 = edge_weight[(size_t)(e + 3) * GAT_H + h];
        const float4 f0 = *reinterpret_cast<const float4*>(node_feat + (size_t)s0 * GAT_ROW + off);
        const float4 f1 = *reinterpret_cast<const float4*>(node_feat + (size_t)s1 * GAT_ROW + off);
        const float4 f2 = *reinterpret_cast<const float4*>(node_feat + (size_t)s2 * GAT_ROW + off);
        const float4 f3 = *reinterpret_cast<const float4*>(node_feat + (size_t)s3 * GAT_ROW + off);
        fma4(acc, f0, w0);
        fma4(acc, f1, w1);
        fma4(acc, f2, w2);
        fma4(acc, f3, w3);
    }
    for (; e < end; ++e) {
        const int   s = col_idx[e];
        const float w = edge_weight[(size_t)e * GAT_H + h];
        const float4 f = *reinterpret_cast<const float4*>(node_feat + (size_t)s * GAT_ROW + off);
        fma4(acc, f, w);
    }

    *reinterpret_cast<float4*>(out + (size_t)node * GAT_ROW + off) = acc;
}

extern "C" void kernel_launch(void* const* d_in, const int* in_sizes, int n_in,
                              void* d_out, int out_size, void* d_ws, size_t ws_size,
                              hipStream_t stream) {
    const int*   row_ptr     = (const int*)d_in[0];
    const int*   col_idx     = (const int*)d_in[1];
    const float* edge_weight = (const float*)d_in[2];
    const float* node_feat   = (const float*)d_in[3];
    float*       out         = (float*)d_out;

    const int num_nodes = in_sizes[0] - 1;          // row_ptr has N+1 entries
    const int blocks = (num_nodes + 3) / 4;         // 4 waves/block, 1 wave/node

    gat_gather_kernel<<<blocks, 256, 0, stream>>>(
        row_ptr, col_idx, edge_weight, node_feat, out, num_nodes);
}